// Round 1
// 7630.738 us; speedup vs baseline: 1.2388x; 1.2388x over previous
//
#include <hip/hip_runtime.h>
#include <math.h>

#define H 1024
#define BATCH 32
#define TSEQ 128
#define VOCAB 32000
#define NROWS (TSEQ*BATCH)   // 4096 rows (t*32+b)
#define NBLK 128             // blocks in persistent LSTM kernel
#define HPB 8                // h-indices per block (NBLK*HPB == H)

typedef float f32x4 __attribute__((ext_vector_type(4)));
typedef __bf16 bf16x8 __attribute__((ext_vector_type(8)));

// count and gen on separate cachelines: 127 pollers must not serialize arrivals
struct Bar { unsigned count; unsigned pad0[31]; unsigned gen; unsigned pad1[31]; };

__device__ __forceinline__ unsigned short f2bf(float f) {
    union { float f; unsigned u; } v; v.f = f;
    unsigned r = v.u + 0x7fffu + ((v.u >> 16) & 1u);  // round-nearest-even
    return (unsigned short)(r >> 16);
}

// async global->LDS, 16B per lane; LDS dest = wave-uniform base + lane*16
__device__ __forceinline__ void gload_lds16(const unsigned short* g, unsigned short* l) {
    __builtin_amdgcn_global_load_lds(
        (const __attribute__((address_space(1))) void*)g,
        (__attribute__((address_space(3))) void*)l, 16, 0, 0);
}

// ---------------- fp32 -> bf16 convert (4-wide) ----------------
__global__ void f2bf4_k(const float* __restrict__ s, unsigned short* __restrict__ d, int n4) {
    int i = blockIdx.x * 256 + threadIdx.x;
    if (i >= n4) return;
    float4 v = reinterpret_cast<const float4*>(s)[i];
    ushort4 o;
    o.x = f2bf(v.x); o.y = f2bf(v.y); o.z = f2bf(v.z); o.w = f2bf(v.w);
    reinterpret_cast<ushort4*>(d)[i] = o;
}

// ---------------- embedding gather -> bf16 ----------------
__global__ void embed_k(const int* __restrict__ tok, const float* __restrict__ emb,
                        unsigned short* __restrict__ x, int n4) {
    int i = blockIdx.x * 256 + threadIdx.x;   // over NROWS * (H/4)
    if (i >= n4) return;
    int r  = i >> 8;            // H/4 == 256
    int k4 = (i & 255) << 2;
    float4 v = *reinterpret_cast<const float4*>(emb + (size_t)tok[r] * H + k4);
    ushort4 o; o.x = f2bf(v.x); o.y = f2bf(v.y); o.z = f2bf(v.z); o.w = f2bf(v.w);
    *reinterpret_cast<ushort4*>(x + (size_t)r * H + k4) = o;
}

// ---------------- per-layer init: h0 -> bf16, barrier reset ----------------
__global__ void init_state_k(const float* __restrict__ h0l,
                             unsigned short* __restrict__ hinit, Bar* bar) {
    int i = blockIdx.x * 256 + threadIdx.x;
    if (i == 0) { bar->count = 0; bar->gen = 0; }
    if (i < BATCH * H) hinit[i] = f2bf(h0l[i]);
}

// ---------------- GEMM: C[M,N] = A[M,K] * W[N,K]^T + bias ----------------
// A,W row-major bf16; direct-fragment loads (no LDS), 128x128 block tile.
__global__ __launch_bounds__(256) void gemm_bt(
    const unsigned short* __restrict__ A,
    const unsigned short* __restrict__ W,
    const float* __restrict__ b1, const float* __restrict__ b2,
    float* __restrict__ C, int M, int N, int K)
{
    int tid  = threadIdx.x;
    int wave = tid >> 6, lane = tid & 63, quad = lane >> 4, l16 = lane & 15;
    int wm = wave >> 1, wn = wave & 1;
    int m0 = blockIdx.y * 128 + wm * 64;
    int n0 = blockIdx.x * 128 + wn * 64;
    f32x4 acc[4][4] = {};
    const unsigned short* Ab = A + (size_t)(m0 + l16) * K + quad * 8;
    const unsigned short* Wb = W + (size_t)(n0 + l16) * K + quad * 8;
    for (int k0 = 0; k0 < K; k0 += 32) {
        bf16x8 a[4], b[4];
#pragma unroll
        for (int i = 0; i < 4; ++i)
            a[i] = *reinterpret_cast<const bf16x8*>(Ab + (size_t)i * 16 * K + k0);
#pragma unroll
        for (int i = 0; i < 4; ++i)
            b[i] = *reinterpret_cast<const bf16x8*>(Wb + (size_t)i * 16 * K + k0);
#pragma unroll
        for (int mi = 0; mi < 4; ++mi)
#pragma unroll
            for (int ni = 0; ni < 4; ++ni)
                acc[mi][ni] = __builtin_amdgcn_mfma_f32_16x16x32_bf16(a[mi], b[ni], acc[mi][ni], 0, 0, 0);
    }
#pragma unroll
    for (int mi = 0; mi < 4; ++mi) {
#pragma unroll
        for (int ni = 0; ni < 4; ++ni) {
            int n = n0 + ni * 16 + l16;
            float bias = (b1 ? b1[n] : 0.f) + (b2 ? b2[n] : 0.f);
#pragma unroll
            for (int r = 0; r < 4; ++r) {
                int m = m0 + mi * 16 + quad * 4 + r;
                C[(size_t)m * N + n] = acc[mi][ni][r] + bias;
            }
        }
    }
}

// ---------------- persistent LSTM layer ----------------
// 128 blocks; block bk owns h-indices [bk*8, bk*8+8) across all 4 gates.
// w_hh slice (32 rows x 1024) lives in LDS for the whole kernel; h(t-1) is
// staged into LDS each step via global_load_lds. LDS layout for both tiles:
// [kk=K/32][row 0..31][32 k-elems] so each wave's ds_read_b128 fragment pull
// is one contiguous 1024B span (conflict-free). c stays in a register:
// thread (cb,cj) owns cell (batch=cb, h=hbase+cj) for all 128 steps.
__global__ __launch_bounds__(256, 1) void lstm_layer_k(
    const float* __restrict__ gates_in,       // [T*B, 4H], includes bias
    const unsigned short* __restrict__ w_hh,  // [4H, H] bf16
    const float* __restrict__ c_init,         // [B*H] layer c0 (fp32)
    float* __restrict__ c_fin,                // [B*H] final c out
    float* __restrict__ h_fin,                // [B*H] final h out
    const unsigned short* __restrict__ h_init,// [B*H] bf16 h0
    unsigned short* __restrict__ h_all,       // [T*B, H] bf16 outputs
    Bar* __restrict__ bar)
{
    __shared__ __align__(16) unsigned short lw[32768];  // 64 KB weights
    __shared__ __align__(16) unsigned short lh[32768];  // 64 KB h(t-1)
    __shared__ float sg[1024];                          // 4 KB gate tile

    const int tid  = threadIdx.x;
    const int bk   = blockIdx.x;
    const int wave = tid >> 6;
    const int lane = tid & 63;
    const int quad = lane >> 4;
    const int l16  = lane & 15;
    const int wm   = wave >> 1;      // m-tile (batch rows wm*16..)
    const int wn   = wave & 1;       // n-tile (block-local cols wn*16..)
    const int hbase = bk * HPB;
    const int cb = tid >> 3;         // cell-update batch index
    const int cj = tid & 7;          // cell-update h index within slice

    // per-lane global element offsets for this lane's 16 staging chunks
    // chunk ch: kk=ch>>7, row=(ch>>2)&31, q=ch&3 -> element row*H + kk*32 + q*8
    int hoff[16];
#pragma unroll
    for (int i = 0; i < 16; ++i) {
        int ch = (wave * 16 + i) * 64 + lane;
        hoff[i] = ((ch >> 2) & 31) * H + (ch >> 7) * 32 + (ch & 3) * 8;
    }

    // load w_hh slice into LDS once; block-local row n=g*8+j <-> global row g*H+hbase+j
#pragma unroll
    for (int i = 0; i < 16; ++i) {
        int ch = (wave * 16 + i) * 64 + lane;
        int n  = (ch >> 2) & 31;
        const unsigned short* src = w_hh
            + (size_t)((n >> 3) * H + hbase + (n & 7)) * H
            + (ch >> 7) * 32 + (ch & 3) * 8;
        gload_lds16(src, &lw[(size_t)(wave * 16 + i) * 64 * 8]);
    }

    float c  = c_init[cb * H + hbase + cj];
    float hl = 0.f;

    const int aoff = (wm * 16 + l16) * 32 + quad * 8;
    const int boff = (wn * 16 + l16) * 32 + quad * 8;

    for (int t = 0; t < TSEQ; ++t) {
        // stage h(t-1) -> lh (h_all row block from previous step, or h0)
        const unsigned short* hsrc = (t == 0) ? h_init
                                              : (h_all + (size_t)(t - 1) * BATCH * H);
#pragma unroll
        for (int i = 0; i < 16; ++i)
            gload_lds16(hsrc + hoff[i], &lh[(size_t)(wave * 16 + i) * 64 * 8]);
        __syncthreads();   // vmcnt(0) drains the LDS-direct loads too

        // prefetch this thread's 4 gate-input values (HBM latency hides under K-loop)
        const float* gp = gates_in + ((size_t)t * BATCH + cb) * (4 * H) + hbase + cj;
        float gi = gp[0], gf = gp[H], gg = gp[2 * H], go = gp[3 * H];

        // 16x16 output tile per wave: C[m=batch][n=block-local gate col]
        f32x4 acc0 = {}, acc1 = {};
#pragma unroll
        for (int kk = 0; kk < 32; kk += 2) {
            bf16x8 va0 = *reinterpret_cast<const bf16x8*>(&lh[kk * 1024 + aoff]);
            bf16x8 vb0 = *reinterpret_cast<const bf16x8*>(&lw[kk * 1024 + boff]);
            acc0 = __builtin_amdgcn_mfma_f32_16x16x32_bf16(va0, vb0, acc0, 0, 0, 0);
            bf16x8 va1 = *reinterpret_cast<const bf16x8*>(&lh[(kk + 1) * 1024 + aoff]);
            bf16x8 vb1 = *reinterpret_cast<const bf16x8*>(&lw[(kk + 1) * 1024 + boff]);
            acc1 = __builtin_amdgcn_mfma_f32_16x16x32_bf16(va1, vb1, acc1, 0, 0, 0);
        }
        f32x4 acc = acc0 + acc1;
#pragma unroll
        for (int r = 0; r < 4; ++r)
            sg[(wm * 16 + quad * 4 + r) * 32 + wn * 16 + l16] = acc[r];
        __syncthreads();

        // cell update: one element per thread; c is register-resident
        float xi = sg[cb * 32 +      cj] + gi;
        float xf = sg[cb * 32 +  8 + cj] + gf;
        float xg = sg[cb * 32 + 16 + cj] + gg;
        float xo = sg[cb * 32 + 24 + cj] + go;
        float i_ = 1.f / (1.f + expf(-xi));
        float f_ = 1.f / (1.f + expf(-xf));
        float g_ = tanhf(xg);
        float o_ = 1.f / (1.f + expf(-xo));
        c  = f_ * c + i_ * g_;
        hl = o_ * tanhf(c);
        h_all[((size_t)t * BATCH + cb) * H + hbase + cj] = f2bf(hl);

        // inter-block barrier (skip after last step)
        if (t < TSEQ - 1) {
            __threadfence();
            __syncthreads();
            if (tid == 0) {
                unsigned v = atomicAdd(&bar->count, 1u);
                if (v == NBLK - 1) {
                    atomicExch(&bar->count, 0u);
                    __threadfence();
                    atomicAdd(&bar->gen, 1u);
                } else {
                    while (atomicAdd(&bar->gen, 0u) < (unsigned)(t + 1))
                        __builtin_amdgcn_s_sleep(8);
                }
            }
            __syncthreads();
            __threadfence();
        }
    }
    c_fin[cb * H + hbase + cj] = c;
    h_fin[cb * H + hbase + cj] = hl;
}

// ---------------- in-place log_softmax, one block per row ----------------
__global__ __launch_bounds__(256) void logsoftmax_k(float* __restrict__ out) {
    float* p = out + (size_t)blockIdx.x * VOCAB;
    int tid = threadIdx.x;
    float m = -INFINITY, s = 0.f;
    for (int j = tid; j < VOCAB; j += 256) {     // 125 iters exactly
        float x = p[j];
        if (x > m) { s = s * expf(m - x) + 1.f; m = x; }
        else         s += expf(x - m);
    }
    __shared__ float sm[256], ss[256];
    sm[tid] = m; ss[tid] = s;
    __syncthreads();
    for (int off = 128; off > 0; off >>= 1) {
        if (tid < off) {
            float m2 = sm[tid + off], s2 = ss[tid + off];
            float M = fmaxf(sm[tid], m2);
            ss[tid] = ss[tid] * expf(sm[tid] - M) + s2 * expf(m2 - M);
            sm[tid] = M;
        }
        __syncthreads();
    }
    float L = sm[0] + logf(ss[0]);
    for (int j = tid; j < VOCAB; j += 256) p[j] -= L;
}

// ---------------- write hN / cN tail ----------------
__global__ void tail_k(const float* __restrict__ hs, const float* __restrict__ cs,
                       float* __restrict__ o) {
    int i = blockIdx.x * 256 + threadIdx.x;
    const int n = 2 * BATCH * H;
    if (i < n) { o[i] = hs[i]; o[n + i] = cs[i]; }
}

extern "C" void kernel_launch(void* const* d_in, const int* in_sizes, int n_in,
                              void* d_out, int out_size, void* d_ws, size_t ws_size,
                              hipStream_t stream)
{
    const int*   tokens = (const int*)  d_in[0];
    const float* h0     = (const float*)d_in[1];
    const float* c0     = (const float*)d_in[2];
    const float* emb    = (const float*)d_in[3];
    const float* w_ih   = (const float*)d_in[4];
    const float* w_hh   = (const float*)d_in[5];
    const float* b_ih   = (const float*)d_in[6];
    const float* b_hh   = (const float*)d_in[7];
    const float* w_dec  = (const float*)d_in[8];
    const float* b_dec  = (const float*)d_in[9];
    float* out = (float*)d_out;

    char* ws = (char*)d_ws;
    size_t off = 0;
    auto alloc = [&](size_t bytes) {
        char* p = ws + off;
        off += (bytes + 255) & ~(size_t)255;
        return p;
    };
    unsigned short* wihb  = (unsigned short*)alloc((size_t)2 * 4 * H * H * 2);
    unsigned short* whhb  = (unsigned short*)alloc((size_t)2 * 4 * H * H * 2);
    unsigned short* wdecb = (unsigned short*)alloc((size_t)VOCAB * H * 2);
    unsigned short* xbf   = (unsigned short*)alloc((size_t)NROWS * H * 2);
    unsigned short* h1bf  = (unsigned short*)alloc((size_t)NROWS * H * 2);
    unsigned short* h2bf  = (unsigned short*)alloc((size_t)NROWS * H * 2);
    float*          gates = (float*)alloc((size_t)NROWS * 4 * H * 4);
    unsigned short* hping = (unsigned short*)alloc((size_t)BATCH * H * 2);
    float*          cst   = (float*)alloc((size_t)2 * BATCH * H * 4);
    float*          hst   = (float*)alloc((size_t)2 * BATCH * H * 4);
    Bar*            bar   = (Bar*)alloc(256);

    // weight / input conversion to bf16
    {
        int n4 = 2 * 4 * H * H / 4;
        f2bf4_k<<<(n4 + 255) / 256, 256, 0, stream>>>(w_ih, wihb, n4);
        f2bf4_k<<<(n4 + 255) / 256, 256, 0, stream>>>(w_hh, whhb, n4);
        int nd4 = VOCAB * H / 4;
        f2bf4_k<<<(nd4 + 255) / 256, 256, 0, stream>>>(w_dec, wdecb, nd4);
        int ne4 = NROWS * H / 4;
        embed_k<<<(ne4 + 255) / 256, 256, 0, stream>>>(tokens, emb, xbf, ne4);
    }

    for (int l = 0; l < 2; ++l) {
        const unsigned short* xin  = (l == 0) ? xbf : h1bf;
        unsigned short*       hall = (l == 0) ? h1bf : h2bf;
        init_state_k<<<(BATCH * H + 255) / 256, 256, 0, stream>>>(
            h0 + (size_t)l * BATCH * H, hping, bar);
        // gates_in = x @ w_ih^T + (b_ih + b_hh)
        gemm_bt<<<dim3(4 * H / 128, NROWS / 128), 256, 0, stream>>>(
            xin, wihb + (size_t)l * 4 * H * H,
            b_ih + (size_t)l * 4 * H, b_hh + (size_t)l * 4 * H,
            gates, NROWS, 4 * H, H);
        lstm_layer_k<<<NBLK, 256, 0, stream>>>(
            gates, whhb + (size_t)l * 4 * H * H,
            c0 + (size_t)l * BATCH * H,
            cst + (size_t)l * BATCH * H, hst + (size_t)l * BATCH * H,
            hping, hall, bar);
    }

    // decoder: logits -> d_out
    gemm_bt<<<dim3(VOCAB / 128, NROWS / 128), 256, 0, stream>>>(
        h2bf, wdecb, b_dec, nullptr, out, NROWS, VOCAB, H);
    logsoftmax_k<<<NROWS, 256, 0, stream>>>(out);
    tail_k<<<(2 * BATCH * H + 255) / 256, 256, 0, stream>>>(hst, cst, out + (size_t)NROWS * VOCAB);
}

// Round 2
// 4711.827 us; speedup vs baseline: 2.0063x; 1.6195x over previous
//
#include <hip/hip_runtime.h>
#include <math.h>

#define H 1024
#define BATCH 32
#define TSEQ 128
#define VOCAB 32000
#define NROWS (TSEQ*BATCH)   // 4096 rows (t*32+b)
#define NBLK 128             // blocks in persistent LSTM kernel
#define HPB 8                // h-indices per block (NBLK*HPB == H)

typedef float f32x4 __attribute__((ext_vector_type(4)));
typedef __bf16 bf16x8 __attribute__((ext_vector_type(8)));
typedef unsigned long long u64;

__device__ __forceinline__ unsigned short f2bf(float f) {
    union { float f; unsigned u; } v; v.f = f;
    unsigned r = v.u + 0x7fffu + ((v.u >> 16) & 1u);  // round-nearest-even
    return (unsigned short)(r >> 16);
}

// async global->LDS, 16B per lane; LDS dest = wave-uniform base + lane*16
__device__ __forceinline__ void gload_lds16(const unsigned short* g, unsigned short* l) {
    __builtin_amdgcn_global_load_lds(
        (const __attribute__((address_space(1))) void*)g,
        (__attribute__((address_space(3))) void*)l, 16, 0, 0);
}

// ---------------- fp32 -> bf16 convert (4-wide) ----------------
__global__ void f2bf4_k(const float* __restrict__ s, unsigned short* __restrict__ d, int n4) {
    int i = blockIdx.x * 256 + threadIdx.x;
    if (i >= n4) return;
    float4 v = reinterpret_cast<const float4*>(s)[i];
    ushort4 o;
    o.x = f2bf(v.x); o.y = f2bf(v.y); o.z = f2bf(v.z); o.w = f2bf(v.w);
    reinterpret_cast<ushort4*>(d)[i] = o;
}

// ---------------- embedding gather -> bf16 ----------------
__global__ void embed_k(const int* __restrict__ tok, const float* __restrict__ emb,
                        unsigned short* __restrict__ x, int n4) {
    int i = blockIdx.x * 256 + threadIdx.x;   // over NROWS * (H/4)
    if (i >= n4) return;
    int r  = i >> 8;            // H/4 == 256
    int k4 = (i & 255) << 2;
    float4 v = *reinterpret_cast<const float4*>(emb + (size_t)tok[r] * H + k4);
    ushort4 o; o.x = f2bf(v.x); o.y = f2bf(v.y); o.z = f2bf(v.z); o.w = f2bf(v.w);
    *reinterpret_cast<ushort4*>(x + (size_t)r * H + k4) = o;
}

// ---------------- per-layer init: h0 -> bf16, barrier counter reset ----------------
__global__ void init_state_k(const float* __restrict__ h0l,
                             unsigned short* __restrict__ hinit, unsigned* cnt) {
    int i = blockIdx.x * 256 + threadIdx.x;
    if (i == 0) *cnt = 0u;
    if (i < BATCH * H) hinit[i] = f2bf(h0l[i]);
}

// ---------------- GEMM: C[M,N] = A[M,K] * W[N,K]^T + bias ----------------
__global__ __launch_bounds__(256) void gemm_bt(
    const unsigned short* __restrict__ A,
    const unsigned short* __restrict__ W,
    const float* __restrict__ b1, const float* __restrict__ b2,
    float* __restrict__ C, int M, int N, int K)
{
    int tid  = threadIdx.x;
    int wave = tid >> 6, lane = tid & 63, quad = lane >> 4, l16 = lane & 15;
    int wm = wave >> 1, wn = wave & 1;
    int m0 = blockIdx.y * 128 + wm * 64;
    int n0 = blockIdx.x * 128 + wn * 64;
    f32x4 acc[4][4] = {};
    const unsigned short* Ab = A + (size_t)(m0 + l16) * K + quad * 8;
    const unsigned short* Wb = W + (size_t)(n0 + l16) * K + quad * 8;
    for (int k0 = 0; k0 < K; k0 += 32) {
        bf16x8 a[4], b[4];
#pragma unroll
        for (int i = 0; i < 4; ++i)
            a[i] = *reinterpret_cast<const bf16x8*>(Ab + (size_t)i * 16 * K + k0);
#pragma unroll
        for (int i = 0; i < 4; ++i)
            b[i] = *reinterpret_cast<const bf16x8*>(Wb + (size_t)i * 16 * K + k0);
#pragma unroll
        for (int mi = 0; mi < 4; ++mi)
#pragma unroll
            for (int ni = 0; ni < 4; ++ni)
                acc[mi][ni] = __builtin_amdgcn_mfma_f32_16x16x32_bf16(a[mi], b[ni], acc[mi][ni], 0, 0, 0);
    }
#pragma unroll
    for (int mi = 0; mi < 4; ++mi) {
#pragma unroll
        for (int ni = 0; ni < 4; ++ni) {
            int n = n0 + ni * 16 + l16;
            float bias = (b1 ? b1[n] : 0.f) + (b2 ? b2[n] : 0.f);
#pragma unroll
            for (int r = 0; r < 4; ++r) {
                int m = m0 + mi * 16 + quad * 4 + r;
                C[(size_t)m * N + n] = acc[mi][ni][r] + bias;
            }
        }
    }
}

// ---------------- persistent LSTM layer ----------------
// 128 blocks; block bk owns h-indices [bk*8, bk*8+8) across all 4 gates.
// w_hh slice (32 rows x 1024) in LDS for the whole kernel. h broadcast goes
// through device-scope (agent) loads/stores that bypass the non-coherent
// per-XCD L2 -- NO threadfence (no L2 writeback/invalidate) anywhere.
// Barrier: one monotonic counter; arrive with relaxed agent RMW, poll with
// relaxed agent LOADS. h_all is indexed by t, so no WAR hazard.
__global__ __launch_bounds__(256, 1) void lstm_layer_k(
    const float* __restrict__ gates_in,       // [T*B, 4H], includes bias
    const unsigned short* __restrict__ w_hh,  // [4H, H] bf16
    const float* __restrict__ c_init,         // [B*H] layer c0 (fp32)
    float* __restrict__ c_fin,                // [B*H] final c out
    float* __restrict__ h_fin,                // [B*H] final h out
    const unsigned short* __restrict__ h_init,// [B*H] bf16 h0
    unsigned short* __restrict__ h_all,       // [T*B, H] bf16 outputs
    unsigned* __restrict__ cnt)
{
    __shared__ __align__(16) unsigned short lw[32768];  // 64 KB weights
    __shared__ __align__(16) unsigned short lh[32768];  // 64 KB h(t-1)
    __shared__ float sg[1024];                          // 4 KB gate tile
    __shared__ unsigned short sgh[256];                 // h bf16 pack buffer

    const int tid  = threadIdx.x;
    const int bk   = blockIdx.x;
    const int wave = tid >> 6;
    const int lane = tid & 63;
    const int quad = lane >> 4;
    const int l16  = lane & 15;
    const int wm   = wave >> 1;      // m-tile (batch rows wm*16..)
    const int wn   = wave & 1;       // n-tile (block-local cols wn*16..)
    const int hbase = bk * HPB;
    const int cb = tid >> 3;         // cell-update batch index
    const int cj = tid & 7;          // cell-update h index within slice

    // load w_hh slice into LDS once (layout [kk][row 0..31][32 k-elems]);
    // block-local row n=g*8+j <-> global row g*H+hbase+j
#pragma unroll
    for (int i = 0; i < 16; ++i) {
        int ch = (wave * 16 + i) * 64 + lane;
        int n  = (ch >> 2) & 31;
        const unsigned short* src = w_hh
            + (size_t)((n >> 3) * H + hbase + (n & 7)) * H
            + (ch >> 7) * 32 + (ch & 3) * 8;
        gload_lds16(src, &lw[(size_t)(wave * 16 + i) * 64 * 8]);
    }

    float c  = c_init[cb * H + hbase + cj];
    float hl = 0.f;

    const int aoff = (wm * 16 + l16) * 32 + quad * 8;
    const int boff = (wn * 16 + l16) * 32 + quad * 8;

    // staging: 8B chunk m = i*256+tid; LDS byte m*8 -> kk=i, row=tid>>3, e=(tid&7)*4
    // global 8B index = row*256 + i*8 + (tid&7)
    const int grow8 = (tid >> 3) * 256 + (tid & 7);
    u64* lhe = reinterpret_cast<u64*>(lh) + tid;   // + i*256

    for (int t = 0; t < TSEQ; ++t) {
        // ---- stage h(t-1) -> lh via device-scope loads (bypass stale L2) ----
        {
            const unsigned short* hsrc = (t == 0) ? h_init
                                                  : (h_all + (size_t)(t - 1) * BATCH * H);
            u64* hsrc8 = const_cast<u64*>(reinterpret_cast<const u64*>(hsrc)) + grow8;
#pragma unroll
            for (int i = 0; i < 32; ++i)
                lhe[i * 256] = __hip_atomic_load(hsrc8 + i * 8,
                                                 __ATOMIC_RELAXED, __HIP_MEMORY_SCOPE_AGENT);
        }
        __syncthreads();

        // prefetch this thread's 4 gate-input values (latency hides under K-loop)
        const float* gp = gates_in + ((size_t)t * BATCH + cb) * (4 * H) + hbase + cj;
        float gi = gp[0], gf = gp[H], gg = gp[2 * H], go = gp[3 * H];

        // 16x16 output tile per wave: C[m=batch][n=block-local gate col]
        f32x4 acc0 = {}, acc1 = {};
#pragma unroll
        for (int kk = 0; kk < 32; kk += 2) {
            bf16x8 va0 = *reinterpret_cast<const bf16x8*>(&lh[kk * 1024 + aoff]);
            bf16x8 vb0 = *reinterpret_cast<const bf16x8*>(&lw[kk * 1024 + boff]);
            acc0 = __builtin_amdgcn_mfma_f32_16x16x32_bf16(va0, vb0, acc0, 0, 0, 0);
            bf16x8 va1 = *reinterpret_cast<const bf16x8*>(&lh[(kk + 1) * 1024 + aoff]);
            bf16x8 vb1 = *reinterpret_cast<const bf16x8*>(&lw[(kk + 1) * 1024 + boff]);
            acc1 = __builtin_amdgcn_mfma_f32_16x16x32_bf16(va1, vb1, acc1, 0, 0, 0);
        }
        f32x4 acc = acc0 + acc1;
#pragma unroll
        for (int r = 0; r < 4; ++r)
            sg[(wm * 16 + quad * 4 + r) * 32 + wn * 16 + l16] = acc[r];
        __syncthreads();

        // ---- cell update: one element per thread; c register-resident ----
        float xi = sg[cb * 32 +      cj] + gi;
        float xf = sg[cb * 32 +  8 + cj] + gf;
        float xg = sg[cb * 32 + 16 + cj] + gg;
        float xo = sg[cb * 32 + 24 + cj] + go;
        float i_ = 1.f / (1.f + expf(-xi));
        float f_ = 1.f / (1.f + expf(-xf));
        float g_ = tanhf(xg);
        float o_ = 1.f / (1.f + expf(-xo));
        c  = f_ * c + i_ * g_;
        hl = o_ * tanhf(c);
        sgh[tid] = f2bf(hl);
        __syncthreads();

        // ---- pack & broadcast h(t): 64 x 8B device-scope stores ----
        if (tid < 64) {
            int b = tid >> 1, half = tid & 1;
            u64 v = reinterpret_cast<const u64*>(sgh)[tid];
            u64* dst = reinterpret_cast<u64*>(h_all + ((size_t)t * BATCH + b) * H + hbase) + half;
            __hip_atomic_store(dst, v, __ATOMIC_RELAXED, __HIP_MEMORY_SCOPE_AGENT);
        }

        // ---- inter-block barrier: arrive (RMW) + load-poll, no fences ----
        if (t < TSEQ - 1) {
            __syncthreads();   // wave 0 drains its h stores (vmcnt 0) before arrival
            if (tid == 0) {
                __hip_atomic_fetch_add(cnt, 1u, __ATOMIC_RELAXED, __HIP_MEMORY_SCOPE_AGENT);
                unsigned tgt = (unsigned)(t + 1) * NBLK;
                while (__hip_atomic_load(cnt, __ATOMIC_RELAXED, __HIP_MEMORY_SCOPE_AGENT) < tgt)
                    __builtin_amdgcn_s_sleep(2);
            }
            __syncthreads();
        }
    }
    c_fin[cb * H + hbase + cj] = c;
    h_fin[cb * H + hbase + cj] = hl;
}

// ---------------- in-place log_softmax, one block per row ----------------
__global__ __launch_bounds__(256) void logsoftmax_k(float* __restrict__ out) {
    float* p = out + (size_t)blockIdx.x * VOCAB;
    int tid = threadIdx.x;
    float m = -INFINITY, s = 0.f;
    for (int j = tid; j < VOCAB; j += 256) {     // 125 iters exactly
        float x = p[j];
        if (x > m) { s = s * expf(m - x) + 1.f; m = x; }
        else         s += expf(x - m);
    }
    __shared__ float sm[256], ss[256];
    sm[tid] = m; ss[tid] = s;
    __syncthreads();
    for (int off = 128; off > 0; off >>= 1) {
        if (tid < off) {
            float m2 = sm[tid + off], s2 = ss[tid + off];
            float M = fmaxf(sm[tid], m2);
            ss[tid] = ss[tid] * expf(sm[tid] - M) + s2 * expf(m2 - M);
            sm[tid] = M;
        }
        __syncthreads();
    }
    float L = sm[0] + logf(ss[0]);
    for (int j = tid; j < VOCAB; j += 256) p[j] -= L;
}

// ---------------- write hN / cN tail ----------------
__global__ void tail_k(const float* __restrict__ hs, const float* __restrict__ cs,
                       float* __restrict__ o) {
    int i = blockIdx.x * 256 + threadIdx.x;
    const int n = 2 * BATCH * H;
    if (i < n) { o[i] = hs[i]; o[n + i] = cs[i]; }
}

extern "C" void kernel_launch(void* const* d_in, const int* in_sizes, int n_in,
                              void* d_out, int out_size, void* d_ws, size_t ws_size,
                              hipStream_t stream)
{
    const int*   tokens = (const int*)  d_in[0];
    const float* h0     = (const float*)d_in[1];
    const float* c0     = (const float*)d_in[2];
    const float* emb    = (const float*)d_in[3];
    const float* w_ih   = (const float*)d_in[4];
    const float* w_hh   = (const float*)d_in[5];
    const float* b_ih   = (const float*)d_in[6];
    const float* b_hh   = (const float*)d_in[7];
    const float* w_dec  = (const float*)d_in[8];
    const float* b_dec  = (const float*)d_in[9];
    float* out = (float*)d_out;

    char* ws = (char*)d_ws;
    size_t off = 0;
    auto alloc = [&](size_t bytes) {
        char* p = ws + off;
        off += (bytes + 255) & ~(size_t)255;
        return p;
    };
    unsigned short* wihb  = (unsigned short*)alloc((size_t)2 * 4 * H * H * 2);
    unsigned short* whhb  = (unsigned short*)alloc((size_t)2 * 4 * H * H * 2);
    unsigned short* wdecb = (unsigned short*)alloc((size_t)VOCAB * H * 2);
    unsigned short* xbf   = (unsigned short*)alloc((size_t)NROWS * H * 2);
    unsigned short* h1bf  = (unsigned short*)alloc((size_t)NROWS * H * 2);
    unsigned short* h2bf  = (unsigned short*)alloc((size_t)NROWS * H * 2);
    float*          gates = (float*)alloc((size_t)NROWS * 4 * H * 4);
    unsigned short* hping = (unsigned short*)alloc((size_t)BATCH * H * 2);
    float*          cst   = (float*)alloc((size_t)2 * BATCH * H * 4);
    float*          hst   = (float*)alloc((size_t)2 * BATCH * H * 4);
    unsigned*       cnt   = (unsigned*)alloc(256);

    // weight / input conversion to bf16
    {
        int n4 = 2 * 4 * H * H / 4;
        f2bf4_k<<<(n4 + 255) / 256, 256, 0, stream>>>(w_ih, wihb, n4);
        f2bf4_k<<<(n4 + 255) / 256, 256, 0, stream>>>(w_hh, whhb, n4);
        int nd4 = VOCAB * H / 4;
        f2bf4_k<<<(nd4 + 255) / 256, 256, 0, stream>>>(w_dec, wdecb, nd4);
        int ne4 = NROWS * H / 4;
        embed_k<<<(ne4 + 255) / 256, 256, 0, stream>>>(tokens, emb, xbf, ne4);
    }

    for (int l = 0; l < 2; ++l) {
        const unsigned short* xin  = (l == 0) ? xbf : h1bf;
        unsigned short*       hall = (l == 0) ? h1bf : h2bf;
        init_state_k<<<(BATCH * H + 255) / 256, 256, 0, stream>>>(
            h0 + (size_t)l * BATCH * H, hping, cnt);
        // gates_in = x @ w_ih^T + (b_ih + b_hh)
        gemm_bt<<<dim3(4 * H / 128, NROWS / 128), 256, 0, stream>>>(
            xin, wihb + (size_t)l * 4 * H * H,
            b_ih + (size_t)l * 4 * H, b_hh + (size_t)l * 4 * H,
            gates, NROWS, 4 * H, H);
        lstm_layer_k<<<NBLK, 256, 0, stream>>>(
            gates, whhb + (size_t)l * 4 * H * H,
            c0 + (size_t)l * BATCH * H,
            cst + (size_t)l * BATCH * H, hst + (size_t)l * BATCH * H,
            hping, hall, cnt);
    }

    // decoder: logits -> d_out
    gemm_bt<<<dim3(VOCAB / 128, NROWS / 128), 256, 0, stream>>>(
        h2bf, wdecb, b_dec, nullptr, out, NROWS, VOCAB, H);
    logsoftmax_k<<<NROWS, 256, 0, stream>>>(out);
    tail_k<<<(2 * BATCH * H + 255) / 256, 256, 0, stream>>>(hst, cst, out + (size_t)NROWS * VOCAB);
}